// Round 2
// baseline (79.242 us; speedup 1.0000x reference)
//
#include <hip/hip_runtime.h>
#include <hip/hip_bf16.h>

// Ball query: for each (b, p) center, collect first S point indices n with
// ||xyz[b,n] - center[b,p]||^2 < r^2 (index order), zero-fill the rest.
//
// FROZEN FP arithmetic (R6, bit-matches harness "np" ref = XLA w/ contraction):
//   cn = fma(cz,cz, fma(cy,cy, cx*cx))          (contracted mul+reduce)
//   xn = fma(z,z,   fma(y,y,   x*x))            (precomputed in pack kernel;
//                                                fp32 store/reload bit-exact)
//   dot= fma(cz,z,  fma(cy,y,  cx*x))           (ascending-K FMA)
//   d2 = (cn + xn) - 2*dot ;  valid = d2 < r2   (all fp32, strict <)
// DO NOT reorder/refactor these ops — a rounding change flips boundary masks.
//
// R20: software-pipelined scan. R19 (4x traffic cut) was a clean null ->
// scan is NOT memory-volume bound; it's bound by the load->compute serial
// dependency: the loop-top early-exit check depends on prev batch's popc
// chain, so next batch's loads can't issue until compute retires
// (~500 cyc/batch critical path; stragglers scanning all 32 batches pay
// 32x that). Fix: ping-pong register double-buffer — prefetch batch k+1
// BEFORE computing batch k; exit check moved after compute. Static va/vb
// (no runtime-indexed arrays -> no scratch). +32 VGPR, still < 128.
// FP sequence / scan order / ballot logic bit-identical to R19.
// Keeps: C=4 centers/wave (R19), XCD-affine swizzle (R18).
// NO global atomics (R9: 7x regression).

typedef float f32x4 __attribute__((ext_vector_type(4)));

__global__ __launch_bounds__(256) void pack_points(
    const float* __restrict__ xyz,   // [B*N, 3]
    f32x4* __restrict__ q,           // [B*N] packed {x,y,z,xn}
    int total)
{
    const int n = blockIdx.x * blockDim.x + threadIdx.x;
    if (n >= total) return;
    const float x = xyz[(size_t)n * 3 + 0];
    const float y = xyz[(size_t)n * 3 + 1];
    const float z = xyz[(size_t)n * 3 + 2];
    // FROZEN xn sequence:
    const float xn = __builtin_fmaf(z, z,
                      __builtin_fmaf(y, y, __fmul_rn(x, x)));
    f32x4 v;
    v[0] = x; v[1] = y; v[2] = z; v[3] = xn;
    q[n] = v;
}

__device__ __forceinline__ void load_batch(
    f32x4 (&dst)[8], const f32x4* __restrict__ qb, int base, int lane)
{
#pragma unroll
    for (int j = 0; j < 8; ++j) {
        dst[j] = qb[base + j * 64 + lane];
    }
}

__device__ __forceinline__ void compute_batch(
    const f32x4 (&v)[8], int n0, int lane,
    const float (&cx)[4], const float (&cy)[4],
    const float (&cz)[4], const float (&cn)[4],
    int (&cnt)[4], int* __restrict__ ob, int S, float r2)
{
    // Per center (wave-uniform skip when full), 8 ballot phases in
    // ascending chunk order — identical order to R18/R19.
#pragma unroll
    for (int i = 0; i < 4; ++i) {
        if (cnt[i] >= S) continue;     // uniform scalar branch
        int cc = cnt[i];
#pragma unroll
        for (int j = 0; j < 8; ++j) {
            const float x = v[j][0], y = v[j][1], z = v[j][2];
            const float xn = v[j][3]; // FROZEN xn (precomputed, bit-exact)
            // FROZEN per-pair FP sequence:
            const float dot = __builtin_fmaf(cz[i], z,
                               __builtin_fmaf(cy[i], y, __fmul_rn(cx[i], x)));
            const float d2 = __fsub_rn(__fadd_rn(cn[i], xn),
                                       __fmul_rn(2.0f, dot));

            const bool valid = d2 < r2;
            const unsigned long long m = __ballot(valid);
            const int rank = __builtin_amdgcn_mbcnt_hi(
                (unsigned)(m >> 32),
                __builtin_amdgcn_mbcnt_lo((unsigned)m, 0u));
            if (valid && (cc + rank) < S) {
                ob[i * S + cc + rank] = n0 + j * 64 + lane;
            }
            cc += __popcll(m);
        }
        cnt[i] = cc;
    }
}

__global__ __launch_bounds__(64) void ball_query_wave4(
    const f32x4* __restrict__ q,          // [B*N] packed {x,y,z,xn}
    const float* __restrict__ center,     // [B, P, 3]
    const float* __restrict__ p_radius,   // [1]
    const int*   __restrict__ p_sample,   // [1]
    int* __restrict__ out,                // [B, P, S]
    int B, int N, int P)
{
    const int S = p_sample[0];
    const float r = p_radius[0];
    const float r2 = __fmul_rn(r, r);

    // XCD-affine swizzle: (blockIdx & 7) = batch slab -> XCD; remaining
    // bits pick a group of 4 consecutive centers (P % 4 == 0).
    const int b = blockIdx.x & 7;
    const int g = blockIdx.x >> 3;         // 0 .. P/4-1
    const int c0 = b * P + g * 4;          // first of 4 centers this wave owns
    const int lane = threadIdx.x;          // 0..63

    // Per-center coords + squared norm (uniform addresses -> scalar loads)
    float cx[4], cy[4], cz[4], cn[4];
    int cnt[4];
#pragma unroll
    for (int i = 0; i < 4; ++i) {
        const size_t c = (size_t)(c0 + i);
        cx[i] = center[c * 3 + 0];
        cy[i] = center[c * 3 + 1];
        cz[i] = center[c * 3 + 2];
        // FROZEN cn sequence:
        cn[i] = __builtin_fmaf(cz[i], cz[i],
                 __builtin_fmaf(cy[i], cy[i], __fmul_rn(cx[i], cx[i])));
        cnt[i] = 0;
    }

    const f32x4* qb = q + (size_t)b * N;
    int* ob = out + (size_t)c0 * S;        // 4*S contiguous output ints

    // Software-pipelined scan: prefetch batch k+1 before computing batch k
    // so straggler waves aren't serialized on load latency. Ping-pong
    // buffers va/vb with static indexing only (no scratch).
    f32x4 va[8], vb[8];
    load_batch(va, qb, 0, lane);
    int n0 = 0;
    for (;;) {
        const int n1 = n0 + 512;
        if (n1 < N) load_batch(vb, qb, n1, lane);
        compute_batch(va, n0, lane, cx, cy, cz, cn, cnt, ob, S, r2);
        if (n1 >= N ||
            (cnt[0] >= S && cnt[1] >= S && cnt[2] >= S && cnt[3] >= S)) break;

        const int n2 = n1 + 512;
        if (n2 < N) load_batch(va, qb, n2, lane);
        compute_batch(vb, n1, lane, cx, cy, cz, cn, cnt, ob, S, r2);
        if (n2 >= N ||
            (cnt[0] >= S && cnt[1] >= S && cnt[2] >= S && cnt[3] >= S)) break;
        n0 = n2;
    }

    // Zero-fill unused slots (harness poisons d_out).
#pragma unroll
    for (int i = 0; i < 4; ++i) {
        int c = cnt[i] > S ? S : cnt[i];
        for (int s = c + lane; s < S; s += 64) {
            ob[i * S + s] = 0;
        }
    }
}

extern "C" void kernel_launch(void* const* d_in, const int* in_sizes, int n_in,
                              void* d_out, int out_size, void* d_ws, size_t ws_size,
                              hipStream_t stream) {
    const float* xyz      = (const float*)d_in[0];   // [B, N, 3]
    const float* center   = (const float*)d_in[1];   // [B, P, 3]
    const float* p_radius = (const float*)d_in[2];   // scalar
    const int*   p_sample = (const int*)d_in[3];     // scalar

    const int B = 8;
    const int N = in_sizes[0] / (B * 3);   // 16384
    const int P = in_sizes[1] / (B * 3);   // 2048

    int* out = (int*)d_out;
    f32x4* q = (f32x4*)d_ws;               // B*N*16 B = 2 MB << ws_size

    // Pass 1: pack {x,y,z,xn}
    const int total = B * N;               // 131072
    pack_points<<<(total + 255) / 256, 256, 0, stream>>>(xyz, q, total);

    // Pass 2: one wave per 4 centers, XCD-affine swizzle.
    const int blocks = B * (P / 4);        // 4096
    ball_query_wave4<<<blocks, 64, 0, stream>>>(
        q, center, p_radius, p_sample, out, B, N, P);
}

// Round 3
// 78.472 us; speedup vs baseline: 1.0098x; 1.0098x over previous
//
#include <hip/hip_runtime.h>

// Ball query: for each (b, p) center, collect first S point indices n with
// ||xyz[b,n] - center[b,p]||^2 < r^2 (index order), zero-fill the rest.
//
// FROZEN FP arithmetic (R6, bit-matches harness "np" ref = XLA w/ contraction):
//   cn = fma(cz,cz, fma(cy,cy, cx*cx))          (contracted mul+reduce)
//   xn = fma(z,z,   fma(y,y,   x*x))            (precomputed in pack kernel;
//                                                fp32 store/reload bit-exact)
//   dot= fma(cz,z,  fma(cy,y,  cx*x))           (ascending-K FMA)
//   d2 = (cn + xn) - 2*dot ;  valid = d2 < r2   (all fp32, strict <)
// DO NOT reorder/refactor these ops — a rounding change flips boundary masks.
// v_pk_*_f32 perform the identical IEEE op per 32-bit half -> bit-exact.
//
// R21: VALU-throughput attack. Evidence: R17 (2x work -> +12.2us) vs
// R19 (4x traffic cut -> null) vs R20 (load pipelining -> null) ==> scan
// is VALU-instruction-bound (~12us). This round halves the FP instruction
// count with VOP3P packed dual-f32 (v_pk_mul/fma/add_f32, 2 IEEE f32
// ops/instr): point buffer repacked as SoA planes X/Y/Z/XN so a lane's
// dwordx4 = 4 consecutive points = 2 aligned pk pairs. Bookkeeping per
// 256-pt group: 4 slot-ballots, one chained 8-instr mbcnt for base rank,
// rank_{s+1}=rank_s+valid_s. Plus: 256-pt early break + scalar all-empty
// fast path (stragglers scan sparse regions -> skip rank/store work).
// Keeps: C=4 centers/wave (R19), XCD-affine swizzle (R18), no ping-pong
// (R20 null). NO global atomics (R9: 7x regression).

typedef float f32x4 __attribute__((ext_vector_type(4)));
typedef float f32x2 __attribute__((ext_vector_type(2)));

// VOP3P dual-f32 helpers — per-half IEEE identical to the scalar ops.
// Register-only asm (no volatile, no memory clobber) -> scheduler-free.
__device__ __forceinline__ f32x2 pk_mul(f32x2 a, f32x2 b) {
    f32x2 d;
    asm("v_pk_mul_f32 %0, %1, %2" : "=v"(d) : "v"(a), "v"(b));
    return d;
}
__device__ __forceinline__ f32x2 pk_fma(f32x2 a, f32x2 b, f32x2 c) {
    f32x2 d;
    asm("v_pk_fma_f32 %0, %1, %2, %3" : "=v"(d) : "v"(a), "v"(b), "v"(c));
    return d;
}
__device__ __forceinline__ f32x2 pk_add(f32x2 a, f32x2 b) {
    f32x2 d;
    asm("v_pk_add_f32 %0, %1, %2" : "=v"(d) : "v"(a), "v"(b));
    return d;
}
__device__ __forceinline__ f32x2 pk_sub(f32x2 a, f32x2 b) {  // a - b, both halves
    f32x2 d;
    asm("v_pk_add_f32 %0, %1, %2 neg_lo:[0,1] neg_hi:[0,1]"
        : "=v"(d) : "v"(a), "v"(b));
    return d;
}

__global__ __launch_bounds__(256) void pack_planes(
    const float* __restrict__ xyz,   // [B*N, 3]
    float* __restrict__ qx, float* __restrict__ qy,
    float* __restrict__ qz, float* __restrict__ qw,
    int total)
{
    const int n = blockIdx.x * blockDim.x + threadIdx.x;
    if (n >= total) return;
    const float x = xyz[(size_t)n * 3 + 0];
    const float y = xyz[(size_t)n * 3 + 1];
    const float z = xyz[(size_t)n * 3 + 2];
    // FROZEN xn sequence:
    const float xn = __builtin_fmaf(z, z,
                      __builtin_fmaf(y, y, __fmul_rn(x, x)));
    qx[n] = x; qy[n] = y; qz[n] = z; qw[n] = xn;
}

// Process one 256-point group (4 consecutive points per lane, slots s=0..3,
// point index = base + 4*lane_within... caller passes base = n0+g*256; the
// lane's slot-s point is base + 4*lane + s, held in pair halves).
__device__ __forceinline__ int process_group(
    f32x2 xlo, f32x2 xhi, f32x2 ylo, f32x2 yhi,
    f32x2 zlo, f32x2 zhi, f32x2 wlo, f32x2 whi,
    int vbase,                         // base + 4*lane (per-lane point index)
    f32x2 pcx, f32x2 pcy, f32x2 pcz, f32x2 pcn, f32x2 p2,
    int cc, int* __restrict__ obi, int S, float r2)
{
    // FROZEN per-pair FP sequence (pk = 2 IEEE f32 ops/instr):
    f32x2 t0 = pk_mul(pcx, xlo);
    t0 = pk_fma(pcy, ylo, t0);
    t0 = pk_fma(pcz, zlo, t0);          // dot, slots 0,1
    f32x2 t1 = pk_mul(pcx, xhi);
    t1 = pk_fma(pcy, yhi, t1);
    t1 = pk_fma(pcz, zhi, t1);          // dot, slots 2,3
    f32x2 a0 = pk_add(pcn, wlo);        // cn + xn
    f32x2 a1 = pk_add(pcn, whi);
    f32x2 b0 = pk_mul(p2, t0);          // 2 * dot
    f32x2 b1 = pk_mul(p2, t1);
    f32x2 d0 = pk_sub(a0, b0);          // d2, slots 0,1
    f32x2 d1 = pk_sub(a1, b1);          // d2, slots 2,3

    const bool v0 = d0[0] < r2;
    const bool v1 = d0[1] < r2;
    const bool v2 = d1[0] < r2;
    const bool v3 = d1[1] < r2;
    const unsigned long long m0 = __ballot(v0);
    const unsigned long long m1 = __ballot(v1);
    const unsigned long long m2 = __ballot(v2);
    const unsigned long long m3 = __ballot(v3);

    // Straggler fast path: sparse region, nothing valid in this group.
    if ((m0 | m1 | m2 | m3) == 0ull) return cc;

    // Base rank for slot 0 of this lane = #valid points in lanes < l over
    // all 4 slots (point order is 4l+s, so any slot of a lower lane
    // precedes every slot of this lane). Chained mbcnt over all 4 masks.
    int R = __builtin_amdgcn_mbcnt_lo((unsigned)m0, 0u);
    R = __builtin_amdgcn_mbcnt_hi((unsigned)(m0 >> 32), R);
    R = __builtin_amdgcn_mbcnt_lo((unsigned)m1, R);
    R = __builtin_amdgcn_mbcnt_hi((unsigned)(m1 >> 32), R);
    R = __builtin_amdgcn_mbcnt_lo((unsigned)m2, R);
    R = __builtin_amdgcn_mbcnt_hi((unsigned)(m2 >> 32), R);
    R = __builtin_amdgcn_mbcnt_lo((unsigned)m3, R);
    R = __builtin_amdgcn_mbcnt_hi((unsigned)(m3 >> 32), R);

    const int rank0 = R;
    const int rank1 = rank0 + (v0 ? 1 : 0);
    const int rank2 = rank1 + (v1 ? 1 : 0);
    const int rank3 = rank2 + (v2 ? 1 : 0);

    const int lim = S - cc;   // ranks >= 0, so lim <= 0 gates everything off
    if (v0 && rank0 < lim) obi[cc + rank0] = vbase + 0;
    if (v1 && rank1 < lim) obi[cc + rank1] = vbase + 1;
    if (v2 && rank2 < lim) obi[cc + rank2] = vbase + 2;
    if (v3 && rank3 < lim) obi[cc + rank3] = vbase + 3;

    cc += __popcll(m0) + __popcll(m1) + __popcll(m2) + __popcll(m3);
    return cc;
}

__global__ __launch_bounds__(64) void ball_query_pk(
    const float* __restrict__ qx, const float* __restrict__ qy,
    const float* __restrict__ qz, const float* __restrict__ qw,
    const float* __restrict__ center,     // [B, P, 3]
    const float* __restrict__ p_radius,   // [1]
    const int*   __restrict__ p_sample,   // [1]
    int* __restrict__ out,                // [B, P, S]
    int B, int N, int P)
{
    const int S = p_sample[0];
    const float r = p_radius[0];
    const float r2 = __fmul_rn(r, r);

    // XCD-affine swizzle: (blockIdx & 7) = batch slab -> XCD; remaining
    // bits pick a group of 4 consecutive centers (P % 4 == 0).
    const int b = blockIdx.x & 7;
    const int g = blockIdx.x >> 3;         // 0 .. P/4-1
    const int c0 = b * P + g * 4;          // first of 4 centers this wave owns
    const int lane = threadIdx.x;          // 0..63

    // Per-center constants, broadcast into pk pairs {v,v}.
    f32x2 pcx[4], pcy[4], pcz[4], pcn[4];
    int cnt[4];
#pragma unroll
    for (int i = 0; i < 4; ++i) {
        const size_t c = (size_t)(c0 + i);
        const float cx = center[c * 3 + 0];
        const float cy = center[c * 3 + 1];
        const float cz = center[c * 3 + 2];
        // FROZEN cn sequence:
        const float cn = __builtin_fmaf(cz, cz,
                          __builtin_fmaf(cy, cy, __fmul_rn(cx, cx)));
        pcx[i][0] = cx; pcx[i][1] = cx;
        pcy[i][0] = cy; pcy[i][1] = cy;
        pcz[i][0] = cz; pcz[i][1] = cz;
        pcn[i][0] = cn; pcn[i][1] = cn;
        cnt[i] = 0;
    }
    f32x2 p2; p2[0] = 2.0f; p2[1] = 2.0f;

    const f32x4* X4 = (const f32x4*)(qx + (size_t)b * N);
    const f32x4* Y4 = (const f32x4*)(qy + (size_t)b * N);
    const f32x4* Z4 = (const f32x4*)(qz + (size_t)b * N);
    const f32x4* W4 = (const f32x4*)(qw + (size_t)b * N);
    int* ob = out + (size_t)c0 * S;        // 4*S contiguous output ints

    // N = 16384 = 32 batches of 512 = 2 groups of 256 each.
    for (int n0 = 0; n0 < N; n0 += 512) {
        if (cnt[0] >= S && cnt[1] >= S && cnt[2] >= S && cnt[3] >= S) break;

        // 8 independent dwordx4 loads (2 groups x 4 planes); lane l holds
        // points {n0 + g*256 + 4l .. +3}.
        const int i0 = (n0 >> 2) + lane;
        const f32x4 xv0 = X4[i0],      yv0 = Y4[i0];
        const f32x4 zv0 = Z4[i0],      wv0 = W4[i0];
        const f32x4 xv1 = X4[i0 + 64], yv1 = Y4[i0 + 64];
        const f32x4 zv1 = Z4[i0 + 64], wv1 = W4[i0 + 64];

        // Split quads into aligned pk pairs (sub-register refs, hoisted
        // out of the center loop).
        f32x2 x0l, x0h, y0l, y0h, z0l, z0h, w0l, w0h;
        f32x2 x1l, x1h, y1l, y1h, z1l, z1h, w1l, w1h;
        x0l[0]=xv0[0]; x0l[1]=xv0[1]; x0h[0]=xv0[2]; x0h[1]=xv0[3];
        y0l[0]=yv0[0]; y0l[1]=yv0[1]; y0h[0]=yv0[2]; y0h[1]=yv0[3];
        z0l[0]=zv0[0]; z0l[1]=zv0[1]; z0h[0]=zv0[2]; z0h[1]=zv0[3];
        w0l[0]=wv0[0]; w0l[1]=wv0[1]; w0h[0]=wv0[2]; w0h[1]=wv0[3];
        x1l[0]=xv1[0]; x1l[1]=xv1[1]; x1h[0]=xv1[2]; x1h[1]=xv1[3];
        y1l[0]=yv1[0]; y1l[1]=yv1[1]; y1h[0]=yv1[2]; y1h[1]=yv1[3];
        z1l[0]=zv1[0]; z1l[1]=zv1[1]; z1h[0]=zv1[2]; z1h[1]=zv1[3];
        w1l[0]=wv1[0]; w1l[1]=wv1[1]; w1h[0]=wv1[2]; w1h[1]=wv1[3];

        const int vbase0 = n0 + 4 * lane;        // lane's slot-0 point index
        const int vbase1 = vbase0 + 256;

        // Per center (wave-uniform skip when full), groups in ascending
        // order; break after group 0 if filled (256-pt exit granularity).
#pragma unroll
        for (int i = 0; i < 4; ++i) {
            if (cnt[i] >= S) continue;     // uniform scalar branch
            int cc = cnt[i];
            cc = process_group(x0l, x0h, y0l, y0h, z0l, z0h, w0l, w0h,
                               vbase0, pcx[i], pcy[i], pcz[i], pcn[i], p2,
                               cc, ob + i * S, S, r2);
            if (cc < S) {
                cc = process_group(x1l, x1h, y1l, y1h, z1l, z1h, w1l, w1h,
                                   vbase1, pcx[i], pcy[i], pcz[i], pcn[i], p2,
                                   cc, ob + i * S, S, r2);
            }
            cnt[i] = cc;
        }
    }

    // Zero-fill unused slots (harness poisons d_out).
#pragma unroll
    for (int i = 0; i < 4; ++i) {
        int c = cnt[i] > S ? S : cnt[i];
        for (int s = c + lane; s < S; s += 64) {
            ob[i * S + s] = 0;
        }
    }
}

extern "C" void kernel_launch(void* const* d_in, const int* in_sizes, int n_in,
                              void* d_out, int out_size, void* d_ws, size_t ws_size,
                              hipStream_t stream) {
    const float* xyz      = (const float*)d_in[0];   // [B, N, 3]
    const float* center   = (const float*)d_in[1];   // [B, P, 3]
    const float* p_radius = (const float*)d_in[2];   // scalar
    const int*   p_sample = (const int*)d_in[3];     // scalar

    const int B = 8;
    const int N = in_sizes[0] / (B * 3);   // 16384
    const int P = in_sizes[1] / (B * 3);   // 2048

    int* out = (int*)d_out;
    const int total = B * N;               // 131072

    // SoA planes in workspace: X, Y, Z, XN — 4 x 512 KB = 2 MB << ws_size.
    float* qx = (float*)d_ws;
    float* qy = qx + total;
    float* qz = qy + total;
    float* qw = qz + total;

    // Pass 1: transpose + precompute xn.
    pack_planes<<<(total + 255) / 256, 256, 0, stream>>>(
        xyz, qx, qy, qz, qw, total);

    // Pass 2: one wave per 4 centers, XCD-affine swizzle.
    const int blocks = B * (P / 4);        // 4096
    ball_query_pk<<<blocks, 64, 0, stream>>>(
        qx, qy, qz, qw, center, p_radius, p_sample, out, B, N, P);
}

// Round 4
// 75.696 us; speedup vs baseline: 1.0468x; 1.0367x over previous
//
#include <hip/hip_runtime.h>

// Ball query: for each (b, p) center, collect first S point indices n with
// ||xyz[b,n] - center[b,p]||^2 < r^2 (index order), zero-fill the rest.
//
// FROZEN FP arithmetic (R6, bit-matches harness "np" ref = XLA w/ contraction):
//   cn = fma(cz,cz, fma(cy,cy, cx*cx))          (contracted mul+reduce)
//   xn = fma(z,z,   fma(y,y,   x*x))            (recomputed inline per batch;
//                                                identical sequence -> identical
//                                                bits as the old store/reload)
//   dot= fma(cz,z,  fma(cy,y,  cx*x))           (ascending-K FMA)
//   d2 = (cn + xn) - 2*dot ;  valid = d2 < r2   (all fp32, strict <)
// DO NOT reorder/refactor these ops — a rounding change flips boundary masks.
//
// R22: single-dispatch fusion. R19/R20/R21 proved memory volume, load
// latency, and VALU count are ALL non-binding for the scan -> the R17
// "~12us slice" must be largely per-dispatch overhead (replay gaps +
// dispatch setup), not kernel content. So: delete the pack pass. A lane's
// 4 consecutive AoS points are 48 B = 3 aligned dwordx4 (slab offset
// b*196608 B and chunk offset (n0+4l)*12 B are both 16B-aligned); unpack
// is free scalar register refs; xn recomputed once per batch (center-
// independent, frozen sequence = bit-exact). Loads drop 8->6 dwordx4 per
// 512-batch; no ws use at all. Bookkeeping (4-slot ballots + chained
// mbcnt + rank_{s+1}=rank_s+valid_s) copied verbatim from R21 (passed).
// Keeps: C=4 centers/wave (R19), XCD-affine swizzle (R18), scalar FP
// (R21's pk was null), no ping-pong (R20 null).
// NO global atomics (R9: 7x regression).

typedef float f32x4 __attribute__((ext_vector_type(4)));

// Process one 256-point group: lane holds 4 consecutive points (slots
// s=0..3, point index vbase+s where vbase = groupbase + 4*lane).
// Returns updated count. Copied from R21 (passed), scalar FP.
__device__ __forceinline__ int process_group(
    float x0, float x1, float x2, float x3,
    float y0, float y1, float y2, float y3,
    float z0, float z1, float z2, float z3,
    float w0, float w1, float w2, float w3,
    int vbase,
    float cx, float cy, float cz, float cn,
    int cc, int* __restrict__ obi, int S, float r2)
{
    // FROZEN per-pair FP sequence, per slot:
    const float dot0 = __builtin_fmaf(cz, z0,
                        __builtin_fmaf(cy, y0, __fmul_rn(cx, x0)));
    const float dot1 = __builtin_fmaf(cz, z1,
                        __builtin_fmaf(cy, y1, __fmul_rn(cx, x1)));
    const float dot2 = __builtin_fmaf(cz, z2,
                        __builtin_fmaf(cy, y2, __fmul_rn(cx, x2)));
    const float dot3 = __builtin_fmaf(cz, z3,
                        __builtin_fmaf(cy, y3, __fmul_rn(cx, x3)));
    const float d20 = __fsub_rn(__fadd_rn(cn, w0), __fmul_rn(2.0f, dot0));
    const float d21 = __fsub_rn(__fadd_rn(cn, w1), __fmul_rn(2.0f, dot1));
    const float d22 = __fsub_rn(__fadd_rn(cn, w2), __fmul_rn(2.0f, dot2));
    const float d23 = __fsub_rn(__fadd_rn(cn, w3), __fmul_rn(2.0f, dot3));

    const bool v0 = d20 < r2;
    const bool v1 = d21 < r2;
    const bool v2 = d22 < r2;
    const bool v3 = d23 < r2;
    const unsigned long long m0 = __ballot(v0);
    const unsigned long long m1 = __ballot(v1);
    const unsigned long long m2 = __ballot(v2);
    const unsigned long long m3 = __ballot(v3);

    // Straggler fast path: sparse region, nothing valid in this group.
    if ((m0 | m1 | m2 | m3) == 0ull) return cc;

    // Base rank for slot 0 of this lane = #valid points in lanes < l over
    // all 4 slots (point order is 4l+s, so any slot of a lower lane
    // precedes every slot of this lane). Chained mbcnt over all 4 masks.
    int R = __builtin_amdgcn_mbcnt_lo((unsigned)m0, 0u);
    R = __builtin_amdgcn_mbcnt_hi((unsigned)(m0 >> 32), R);
    R = __builtin_amdgcn_mbcnt_lo((unsigned)m1, R);
    R = __builtin_amdgcn_mbcnt_hi((unsigned)(m1 >> 32), R);
    R = __builtin_amdgcn_mbcnt_lo((unsigned)m2, R);
    R = __builtin_amdgcn_mbcnt_hi((unsigned)(m2 >> 32), R);
    R = __builtin_amdgcn_mbcnt_lo((unsigned)m3, R);
    R = __builtin_amdgcn_mbcnt_hi((unsigned)(m3 >> 32), R);

    const int rank0 = R;
    const int rank1 = rank0 + (v0 ? 1 : 0);
    const int rank2 = rank1 + (v1 ? 1 : 0);
    const int rank3 = rank2 + (v2 ? 1 : 0);

    const int lim = S - cc;   // ranks >= 0, so lim <= 0 gates everything off
    if (v0 && rank0 < lim) obi[cc + rank0] = vbase + 0;
    if (v1 && rank1 < lim) obi[cc + rank1] = vbase + 1;
    if (v2 && rank2 < lim) obi[cc + rank2] = vbase + 2;
    if (v3 && rank3 < lim) obi[cc + rank3] = vbase + 3;

    cc += __popcll(m0) + __popcll(m1) + __popcll(m2) + __popcll(m3);
    return cc;
}

__global__ __launch_bounds__(64) void ball_query_fused(
    const float* __restrict__ xyz,        // [B, N, 3]
    const float* __restrict__ center,     // [B, P, 3]
    const float* __restrict__ p_radius,   // [1]
    const int*   __restrict__ p_sample,   // [1]
    int* __restrict__ out,                // [B, P, S]
    int B, int N, int P)
{
    const int S = p_sample[0];
    const float r = p_radius[0];
    const float r2 = __fmul_rn(r, r);

    // XCD-affine swizzle: (blockIdx & 7) = batch slab -> XCD; remaining
    // bits pick a group of 4 consecutive centers (P % 4 == 0).
    const int b = blockIdx.x & 7;
    const int g = blockIdx.x >> 3;         // 0 .. P/4-1
    const int c0 = b * P + g * 4;          // first of 4 centers this wave owns
    const int lane = threadIdx.x;          // 0..63

    // Per-center coords + squared norm (uniform addresses -> scalar loads)
    float cx[4], cy[4], cz[4], cn[4];
    int cnt[4];
#pragma unroll
    for (int i = 0; i < 4; ++i) {
        const size_t c = (size_t)(c0 + i);
        cx[i] = center[c * 3 + 0];
        cy[i] = center[c * 3 + 1];
        cz[i] = center[c * 3 + 2];
        // FROZEN cn sequence:
        cn[i] = __builtin_fmaf(cz[i], cz[i],
                 __builtin_fmaf(cy[i], cy[i], __fmul_rn(cx[i], cx[i])));
        cnt[i] = 0;
    }

    // Raw AoS slab for this batch index: 3 dwordx4 per lane cover the
    // lane's 4 consecutive points {x0 y0 z0 x1 | y1 z1 x2 y2 | z2 x3 y3 z3}.
    // Slab offset b*N*3*4 B = b*196608 B and lane chunk (n0+4l)*12 B are
    // 16B-aligned -> dwordx4 legal.
    const f32x4* xb4 = (const f32x4*)(xyz + (size_t)b * N * 3);
    int* ob = out + (size_t)c0 * S;        // 4*S contiguous output ints

    // N = 16384 = 32 batches of 512 = 2 groups of 256 each.
    for (int n0 = 0; n0 < N; n0 += 512) {
        if (cnt[0] >= S && cnt[1] >= S && cnt[2] >= S && cnt[3] >= S) break;

        // 6 independent dwordx4 loads (2 groups x 3 quads) — all in flight.
        const int qi0 = 3 * ((n0 >> 2) + lane);   // f32x4 index of group-0 chunk
        const f32x4 a0 = xb4[qi0 + 0];
        const f32x4 a1 = xb4[qi0 + 1];
        const f32x4 a2 = xb4[qi0 + 2];
        const f32x4 b0 = xb4[qi0 + 192];          // group 1: +256 pts = +192 quads
        const f32x4 b1 = xb4[qi0 + 193];
        const f32x4 b2 = xb4[qi0 + 194];

        // Free scalar unpack (register refs, no pairing constraints).
        const float gx0 = a0[0], gy0 = a0[1], gz0 = a0[2];
        const float gx1 = a0[3], gy1 = a1[0], gz1 = a1[1];
        const float gx2 = a1[2], gy2 = a1[3], gz2 = a2[0];
        const float gx3 = a2[1], gy3 = a2[2], gz3 = a2[3];
        const float hx0 = b0[0], hy0 = b0[1], hz0 = b0[2];
        const float hx1 = b0[3], hy1 = b1[0], hz1 = b1[1];
        const float hx2 = b1[2], hy2 = b1[3], hz2 = b2[0];
        const float hx3 = b2[1], hy3 = b2[2], hz3 = b2[3];

        // FROZEN xn sequence — center-independent, once per batch,
        // bit-identical to the old pack-kernel store/reload:
        const float gw0 = __builtin_fmaf(gz0, gz0,
                           __builtin_fmaf(gy0, gy0, __fmul_rn(gx0, gx0)));
        const float gw1 = __builtin_fmaf(gz1, gz1,
                           __builtin_fmaf(gy1, gy1, __fmul_rn(gx1, gx1)));
        const float gw2 = __builtin_fmaf(gz2, gz2,
                           __builtin_fmaf(gy2, gy2, __fmul_rn(gx2, gx2)));
        const float gw3 = __builtin_fmaf(gz3, gz3,
                           __builtin_fmaf(gy3, gy3, __fmul_rn(gx3, gx3)));
        const float hw0 = __builtin_fmaf(hz0, hz0,
                           __builtin_fmaf(hy0, hy0, __fmul_rn(hx0, hx0)));
        const float hw1 = __builtin_fmaf(hz1, hz1,
                           __builtin_fmaf(hy1, hy1, __fmul_rn(hx1, hx1)));
        const float hw2 = __builtin_fmaf(hz2, hz2,
                           __builtin_fmaf(hy2, hy2, __fmul_rn(hx2, hx2)));
        const float hw3 = __builtin_fmaf(hz3, hz3,
                           __builtin_fmaf(hy3, hy3, __fmul_rn(hx3, hx3)));

        const int vbase0 = n0 + 4 * lane;        // lane's slot-0 point index
        const int vbase1 = vbase0 + 256;

        // Per center (wave-uniform skip when full), groups in ascending
        // order; stop after group 0 if filled (256-pt exit granularity).
#pragma unroll
        for (int i = 0; i < 4; ++i) {
            if (cnt[i] >= S) continue;     // uniform scalar branch
            int cc = cnt[i];
            cc = process_group(gx0, gx1, gx2, gx3,
                               gy0, gy1, gy2, gy3,
                               gz0, gz1, gz2, gz3,
                               gw0, gw1, gw2, gw3,
                               vbase0, cx[i], cy[i], cz[i], cn[i],
                               cc, ob + i * S, S, r2);
            if (cc < S) {
                cc = process_group(hx0, hx1, hx2, hx3,
                                   hy0, hy1, hy2, hy3,
                                   hz0, hz1, hz2, hz3,
                                   hw0, hw1, hw2, hw3,
                                   vbase1, cx[i], cy[i], cz[i], cn[i],
                                   cc, ob + i * S, S, r2);
            }
            cnt[i] = cc;
        }
    }

    // Zero-fill unused slots (harness poisons d_out).
#pragma unroll
    for (int i = 0; i < 4; ++i) {
        int c = cnt[i] > S ? S : cnt[i];
        for (int s = c + lane; s < S; s += 64) {
            ob[i * S + s] = 0;
        }
    }
}

extern "C" void kernel_launch(void* const* d_in, const int* in_sizes, int n_in,
                              void* d_out, int out_size, void* d_ws, size_t ws_size,
                              hipStream_t stream) {
    const float* xyz      = (const float*)d_in[0];   // [B, N, 3]
    const float* center   = (const float*)d_in[1];   // [B, P, 3]
    const float* p_radius = (const float*)d_in[2];   // scalar
    const int*   p_sample = (const int*)d_in[3];     // scalar

    const int B = 8;
    const int N = in_sizes[0] / (B * 3);   // 16384
    const int P = in_sizes[1] / (B * 3);   // 2048

    int* out = (int*)d_out;
    (void)d_ws; (void)ws_size;             // no workspace needed anymore

    // Single dispatch: one wave per 4 centers, XCD-affine swizzle.
    const int blocks = B * (P / 4);        // 4096
    ball_query_fused<<<blocks, 64, 0, stream>>>(
        xyz, center, p_radius, p_sample, out, B, N, P);
}